// Round 5
// baseline (220.014 us; speedup 1.0000x reference)
//
#include <hip/hip_runtime.h>

typedef unsigned short u16;
typedef unsigned int u32;
typedef short bf16x8 __attribute__((ext_vector_type(8)));
typedef float f32x4 __attribute__((ext_vector_type(4)));

// float -> bf16 bits, round-to-nearest-even (inputs never NaN here)
__device__ __forceinline__ u16 f2bf(float f) {
  union { float f; unsigned int u; } a; a.f = f;
  unsigned int r = a.u + 0x7FFFu + ((a.u >> 16) & 1u);
  return (u16)(r >> 16);
}

// ---- K1/K5: Y[o][p] = sum_c W[o*192+c] * X[c*4096+p]; o-tile = OT rows ----
// OT sized for occupancy: grid_y = (M/OT); keep >= 3 blocks/CU resident.
template <int OT>
__global__ __launch_bounds__(256) void gemm192(const float* __restrict__ W,
                                               const float* __restrict__ X,
                                               float* __restrict__ Y) {
  __shared__ float wlds[OT * 192];
  int tid = threadIdx.x;
  int p = blockIdx.x * 256 + tid;
  int o0 = blockIdx.y * OT;
  for (int i = tid; i < OT * 192; i += 256) wlds[i] = W[o0 * 192 + i];
  __syncthreads();
  float acc[OT];
  #pragma unroll
  for (int i = 0; i < OT; ++i) acc[i] = 0.f;
  // software-pipelined: X loads for c+4 issued before FMAs of c
  float x0 = X[0 * 4096 + p];
  float x1 = X[1 * 4096 + p];
  float x2 = X[2 * 4096 + p];
  float x3 = X[3 * 4096 + p];
  for (int c = 0; c < 192; c += 4) {
    float n0, n1, n2, n3;
    if (c < 188) {
      n0 = X[(c + 4) * 4096 + p];
      n1 = X[(c + 5) * 4096 + p];
      n2 = X[(c + 6) * 4096 + p];
      n3 = X[(c + 7) * 4096 + p];
    }
    #pragma unroll
    for (int oo = 0; oo < OT; ++oo) {
      const float4* wv = (const float4*)&wlds[oo * 192 + c];  // broadcast b128
      acc[oo] = fmaf(wv->x, x0, fmaf(wv->y, x1, fmaf(wv->z, x2, fmaf(wv->w, x3, acc[oo]))));
    }
    x0 = n0; x1 = n1; x2 = n2; x3 = n3;
  }
  #pragma unroll
  for (int oo = 0; oo < OT; ++oo) Y[(size_t)(o0 + oo) * 4096 + p] = acc[oo];
}

// ---- K2: depthwise 3x3, pad=1, on [576][64][64] ----
__global__ __launch_bounds__(256) void dwconv3(const float* __restrict__ in,
                                               const float* __restrict__ w,
                                               float* __restrict__ out) {
  int idx = blockIdx.x * 256 + threadIdx.x;  // c*4096 + p
  int c = idx >> 12;
  int p = idx & 4095;
  int y = p >> 6, x = p & 63;
  const float* wc = w + c * 9;
  const float* ic = in + (size_t)c * 4096;
  float s = 0.f;
  #pragma unroll
  for (int i = 0; i < 3; ++i) {
    int yy = y + i - 1;
    if ((unsigned)yy >= 64u) continue;
    #pragma unroll
    for (int j = 0; j < 3; ++j) {
      int xx = x + j - 1;
      if ((unsigned)xx >= 64u) continue;
      s = fmaf(wc[i * 3 + j], ic[yy * 64 + xx], s);
    }
  }
  out[idx] = s;
}

// ---- K3: fused normalize+pack. 256 blocks; per block: 128 pixels of one head.
// Threads 0..127: Q+K normalize+pack ([h][p][32] bf16). Threads 128..255: V pack
// (k-permuted [h][d][k'], row d==24 = ones -> PV MFMA yields softmax denominator).
__global__ __launch_bounds__(256) void nvpack(const float* __restrict__ qkv,
                                              u32* __restrict__ Qh32,
                                              u32* __restrict__ Kh32,
                                              u32* __restrict__ Vt32) {
  __shared__ u32 Ql[128 * 17];
  __shared__ u32 Kl[128 * 17];
  __shared__ u16 Vl[32 * 128];
  int t = threadIdx.x;
  int bid = blockIdx.x;          // 256 blocks
  int h = bid >> 5;
  int p0 = (bid & 31) << 7;      // 128-pixel tile
  u32* Vl32 = (u32*)Vl;
  const float QSC = 0.20412414523193154f * 1.4426950408889634f;  // 24^-0.5 * log2(e)
  if (t < 128) {
    int p = p0 + t;
    float qv[24], kv[24];
    float sq = 0.f, sk = 0.f;
    #pragma unroll
    for (int d = 0; d < 24; ++d) {
      qv[d] = qkv[(size_t)(h * 24 + d) * 4096 + p];
      sq = fmaf(qv[d], qv[d], sq);
    }
    #pragma unroll
    for (int d = 0; d < 24; ++d) {
      kv[d] = qkv[(size_t)(192 + h * 24 + d) * 4096 + p];
      sk = fmaf(kv[d], kv[d], sk);
    }
    float iq = QSC / fmaxf(sqrtf(sq), 1e-12f);  // F.normalize: x / max(||x||, eps)
    float ik = 1.0f / fmaxf(sqrtf(sk), 1e-12f);
    u32* qrow = Ql + t * 17;
    u32* krow = Kl + t * 17;
    #pragma unroll
    for (int j = 0; j < 12; ++j) {
      qrow[j] = ((u32)f2bf(qv[2 * j + 1] * iq) << 16) | f2bf(qv[2 * j] * iq);
      krow[j] = ((u32)f2bf(kv[2 * j + 1] * ik) << 16) | f2bf(kv[2 * j] * ik);
    }
    #pragma unroll
    for (int j = 12; j < 16; ++j) { qrow[j] = 0; krow[j] = 0; }
  } else {
    int tl = t - 128;
    int p = p0 + tl;
    int kp = (tl & ~63) | (((tl & 15) << 1) + ((tl >> 4) & 1) + (tl & 32));
    #pragma unroll
    for (int d = 0; d < 24; ++d)
      Vl[d * 128 + kp] = f2bf(qkv[(size_t)(384 + h * 24 + d) * 4096 + p]);
    Vl[24 * 128 + kp] = 0x3F80;  // bf16 1.0
  }
  for (int i = t; i < 7 * 64; i += 256) Vl32[25 * 64 + i] = 0;  // zero d=25..31
  __syncthreads();
  size_t base = ((size_t)(h << 12) + p0) * 16;
  for (int i = t; i < 2048; i += 256) {
    u32 li = (i >> 4) * 17 + (i & 15);
    Qh32[base + i] = Ql[li];
    Kh32[base + i] = Kl[li];
  }
  for (int i = t; i < 2048; i += 256) {
    int d = i >> 6, c = i & 63;
    Vt32[(((size_t)(h * 32 + d)) << 11) + (p0 >> 1) + c] = Vl32[d * 64 + c];
  }
}

#define PSTR 36  // dwords per P row (16B-aligned rows, 2-way-free banks)

// ---- K4: flash attention, 128 q/block (2 frags/wave), split-K 8, no barriers.
// No online max (logits bounded +-0.295 after log2e fold). Single P buffer (wave-
// private strips, in-order LDS). Epilogue: device-scope atomicAdd of numerator
// [h][q][24] and denominator [h][q] (additive across splits; buffers pre-zeroed).
__global__ __launch_bounds__(256, 8) void attn(const u16* __restrict__ Qh,
                                               const u16* __restrict__ Kh,
                                               const u16* __restrict__ Vt,
                                               float* __restrict__ pnum,
                                               float* __restrict__ pden) {
  __shared__ u32 Pl[128 * PSTR];  // 18432 B -> 8 blocks/CU
  int tid = threadIdx.x;
  int wave = tid >> 6, lane = tid & 63;
  int lo = lane & 15, hi = lane >> 4;
  int b = blockIdx.x;
  int head = b & 7;              // head == XCD (round-robin) -> K/V L2-resident per XCD
  int t = b >> 3;
  int q0 = (t & 31) << 7;        // 32 q-tiles of 128
  int ks = t >> 5;               // 0..7
  int kbase = ks << 9;           // 512 keys per split

  const u16* Kb = Kh + ((size_t)head << 17);
  const u16* Vb = Vt + ((size_t)head << 17);

  size_t qbase = ((size_t)(head << 12) + q0 + wave * 32 + lo) << 5;
  bf16x8 qf0 = *(const bf16x8*)(Qh + qbase + hi * 8);
  bf16x8 qf1 = *(const bf16x8*)(Qh + qbase + (16 << 5) + hi * 8);

  f32x4 o00 = {0.f, 0.f, 0.f, 0.f}, o01 = o00, o10 = o00, o11 = o00;

  int wr0 = (wave * 32 + hi * 4) * PSTR + lo;   // frag0 write base (dwords)
  int rd0 = (wave * 32 + lo) * PSTR + hi * 4;   // frag0 read base (dwords)

  bf16x8 kf[2][4];
  #pragma unroll
  for (int j = 0; j < 4; ++j)
    kf[0][j] = *(const bf16x8*)(Kb + (((size_t)(kbase + j * 16 + lo)) << 5) + hi * 8);

  #pragma unroll
  for (int it = 0; it < 8; ++it) {
    int cur = it & 1;
    int k0 = kbase + it * 64;
    // V for CURRENT iter (consumed at bottom, ~full body of latency cover)
    bf16x8 vf[4];
    #pragma unroll
    for (int c = 0; c < 2; ++c)
      #pragma unroll
      for (int n = 0; n < 2; ++n)
        vf[c * 2 + n] = *(const bf16x8*)(Vb + (((size_t)(n * 16 + lo)) << 12) + k0 + c * 32 + hi * 8);
    // K for NEXT iter
    if (it < 7) {
      #pragma unroll
      for (int j = 0; j < 4; ++j)
        kf[cur ^ 1][j] = *(const bf16x8*)(Kb + (((size_t)(k0 + 64 + j * 16 + lo)) << 5) + hi * 8);
    }

    f32x4 z = {0.f, 0.f, 0.f, 0.f};
    f32x4 s00 = __builtin_amdgcn_mfma_f32_16x16x32_bf16(qf0, kf[cur][0], z, 0, 0, 0);
    f32x4 s01 = __builtin_amdgcn_mfma_f32_16x16x32_bf16(qf0, kf[cur][1], z, 0, 0, 0);
    f32x4 s02 = __builtin_amdgcn_mfma_f32_16x16x32_bf16(qf0, kf[cur][2], z, 0, 0, 0);
    f32x4 s03 = __builtin_amdgcn_mfma_f32_16x16x32_bf16(qf0, kf[cur][3], z, 0, 0, 0);
    f32x4 s10 = __builtin_amdgcn_mfma_f32_16x16x32_bf16(qf1, kf[cur][0], z, 0, 0, 0);
    f32x4 s11 = __builtin_amdgcn_mfma_f32_16x16x32_bf16(qf1, kf[cur][1], z, 0, 0, 0);
    f32x4 s12 = __builtin_amdgcn_mfma_f32_16x16x32_bf16(qf1, kf[cur][2], z, 0, 0, 0);
    f32x4 s13 = __builtin_amdgcn_mfma_f32_16x16x32_bf16(qf1, kf[cur][3], z, 0, 0, 0);

    // frag0: exp + truncate-pack + LDS write, then read (latency covered by frag1 work)
    #pragma unroll
    for (int r = 0; r < 4; ++r) {
      u32 e0 = __float_as_uint(__builtin_amdgcn_exp2f(s00[r]));
      u32 e1 = __float_as_uint(__builtin_amdgcn_exp2f(s01[r]));
      u32 e2 = __float_as_uint(__builtin_amdgcn_exp2f(s02[r]));
      u32 e3 = __float_as_uint(__builtin_amdgcn_exp2f(s03[r]));
      Pl[wr0 + r * PSTR]      = __builtin_amdgcn_perm(e1, e0, 0x07060302u);
      Pl[wr0 + r * PSTR + 16] = __builtin_amdgcn_perm(e3, e2, 0x07060302u);
    }
    bf16x8 a00 = *(const bf16x8*)(&Pl[rd0]);
    bf16x8 a01 = *(const bf16x8*)(&Pl[rd0 + 16]);
    // frag1
    #pragma unroll
    for (int r = 0; r < 4; ++r) {
      u32 e0 = __float_as_uint(__builtin_amdgcn_exp2f(s10[r]));
      u32 e1 = __float_as_uint(__builtin_amdgcn_exp2f(s11[r]));
      u32 e2 = __float_as_uint(__builtin_amdgcn_exp2f(s12[r]));
      u32 e3 = __float_as_uint(__builtin_amdgcn_exp2f(s13[r]));
      Pl[wr0 + 16 * PSTR + r * PSTR]      = __builtin_amdgcn_perm(e1, e0, 0x07060302u);
      Pl[wr0 + 16 * PSTR + r * PSTR + 16] = __builtin_amdgcn_perm(e3, e2, 0x07060302u);
    }
    bf16x8 a10 = *(const bf16x8*)(&Pl[rd0 + 16 * PSTR]);
    bf16x8 a11 = *(const bf16x8*)(&Pl[rd0 + 16 * PSTR + 16]);

    o00 = __builtin_amdgcn_mfma_f32_16x16x32_bf16(a00, vf[0], o00, 0, 0, 0);
    o01 = __builtin_amdgcn_mfma_f32_16x16x32_bf16(a00, vf[1], o01, 0, 0, 0);
    o10 = __builtin_amdgcn_mfma_f32_16x16x32_bf16(a10, vf[0], o10, 0, 0, 0);
    o11 = __builtin_amdgcn_mfma_f32_16x16x32_bf16(a10, vf[1], o11, 0, 0, 0);
    o00 = __builtin_amdgcn_mfma_f32_16x16x32_bf16(a01, vf[2], o00, 0, 0, 0);
    o01 = __builtin_amdgcn_mfma_f32_16x16x32_bf16(a01, vf[3], o01, 0, 0, 0);
    o10 = __builtin_amdgcn_mfma_f32_16x16x32_bf16(a11, vf[2], o10, 0, 0, 0);
    o11 = __builtin_amdgcn_mfma_f32_16x16x32_bf16(a11, vf[3], o11, 0, 0, 0);
  }

  // epilogue: C-layout atomic accumulate. d = lo (o*0), 16+lo (o*1, lo<8);
  // lo==8 of o*1 is the ones-row (denominator) sum.
  size_t qg = ((size_t)head << 12) + q0 + wave * 32 + hi * 4;
  #pragma unroll
  for (int r = 0; r < 4; ++r) {
    float* row0 = pnum + (qg + r) * 24;
    atomicAdd(&row0[lo], o00[r]);
    if (lo < 8) atomicAdd(&row0[16 + lo], o01[r]);
    if (lo == 8) atomicAdd(&pden[qg + r], o01[r]);
    float* row1 = pnum + (qg + 16 + r) * 24;
    atomicAdd(&row1[lo], o10[r]);
    if (lo < 8) atomicAdd(&row1[16 + lo], o11[r]);
    if (lo == 8) atomicAdd(&pden[qg + 16 + r], o11[r]);
  }
}

// ---- K4b: normalize numerators -> attn_o [192][4096] ----
__global__ __launch_bounds__(256) void combine(const float* __restrict__ pnum,
                                               const float* __restrict__ pden,
                                               float* __restrict__ Y) {
  int idx = blockIdx.x * 256 + threadIdx.x;  // (h,q): 8*4096
  int h = idx >> 12, q = idx & 4095;
  int dg = blockIdx.y * 8;
  const float* row = pnum + (size_t)idx * 24 + dg;
  float inv = 1.0f / pden[idx];
  float4 v0 = *(const float4*)(row);
  float4 v1 = *(const float4*)(row + 4);
  Y[(size_t)(h * 24 + dg + 0) * 4096 + q] = v0.x * inv;
  Y[(size_t)(h * 24 + dg + 1) * 4096 + q] = v0.y * inv;
  Y[(size_t)(h * 24 + dg + 2) * 4096 + q] = v0.z * inv;
  Y[(size_t)(h * 24 + dg + 3) * 4096 + q] = v0.w * inv;
  Y[(size_t)(h * 24 + dg + 4) * 4096 + q] = v1.x * inv;
  Y[(size_t)(h * 24 + dg + 5) * 4096 + q] = v1.y * inv;
  Y[(size_t)(h * 24 + dg + 6) * 4096 + q] = v1.z * inv;
  Y[(size_t)(h * 24 + dg + 7) * 4096 + q] = v1.w * inv;
}

extern "C" void kernel_launch(void* const* d_in, const int* in_sizes, int n_in,
                              void* d_out, int out_size, void* d_ws, size_t ws_size,
                              hipStream_t stream) {
  const float* x      = (const float*)d_in[0];  // [192][4096]
  const float* w_qkv  = (const float*)d_in[1];  // [576][192]
  const float* w_dw   = (const float*)d_in[2];  // [576][9]
  const float* w_proj = (const float*)d_in[3];  // [192][192]
  float* out = (float*)d_out;                   // [192][4096] fp32

  char* ws = (char*)d_ws;
  float* qkv    = (float*)(ws);                 // 9437184           (dead after dwconv3)
  float* qkvd   = (float*)(ws + 9437184);       // 9437184           (dead after nvpack)
  u16*   Qh     = (u16*)  (ws + 18874368);      // 2097152
  u16*   Kh     = (u16*)  (ws + 20971520);      // 2097152
  u16*   Vt     = (u16*)  (ws + 23068672);      // 2097152  (end 25165824)
  // reuse the qkv region (dead after dwconv3) for attention accumulators:
  float* pnum   = (float*)(ws);                 // 8*4096*24*4 = 3145728
  float* pden   = (float*)(ws + 3145728);       // 8*4096*4   = 131072
  float* attn_o = (float*)(ws + 3276800);       // 192*4096*4 = 3145728 (end 6422528 < qkvd)

  // qkv GEMM, OT=8: grid (16,72)=1152 blocks = 4.5 blocks/CU
  gemm192<8><<<dim3(16, 72), 256, 0, stream>>>(w_qkv, x, qkv);
  dwconv3<<<dim3(9216), 256, 0, stream>>>(qkv, w_dw, qkvd);
  // zero attention accumulators (qkv region now dead; stream order guarantees safety)
  hipMemsetAsync(pnum, 0, 3145728 + 131072, stream);
  nvpack<<<dim3(256), 256, 0, stream>>>(qkvd, (u32*)Qh, (u32*)Kh, (u32*)Vt);
  attn<<<dim3(2048), 256, 0, stream>>>(Qh, Kh, Vt, pnum, pden);
  combine<<<dim3(128, 3), 256, 0, stream>>>(pnum, pden, attn_o);
  // proj GEMM, OT=4: grid (16,48)=768 blocks = 3 blocks/CU
  gemm192<4><<<dim3(16, 48), 256, 0, stream>>>(w_proj, attn_o, out);
}

// Round 6
// 198.311 us; speedup vs baseline: 1.1094x; 1.1094x over previous
//
#include <hip/hip_runtime.h>

typedef unsigned short u16;
typedef unsigned int u32;
typedef short bf16x8 __attribute__((ext_vector_type(8)));
typedef float f32x4 __attribute__((ext_vector_type(4)));

// float -> bf16 bits, round-to-nearest-even (inputs never NaN here)
__device__ __forceinline__ u16 f2bf(float f) {
  union { float f; unsigned int u; } a; a.f = f;
  unsigned int r = a.u + 0x7FFFu + ((a.u >> 16) & 1u);
  return (u16)(r >> 16);
}

// float -> fp16 bits / back (partial accumulators; |x| <= ~1e3, well inside fp16)
__device__ __forceinline__ u16 f2h(float f) {
  _Float16 h = (_Float16)f;
  return *(u16*)&h;
}
__device__ __forceinline__ float h2f(u16 b) {
  _Float16 h = *(_Float16*)&b;
  return (float)h;
}

// ---- K1/K5: Y[o][p] = sum_c W[o*192+c] * X[c*4096+p]; o-tile = OT rows ----
template <int OT>
__global__ __launch_bounds__(256) void gemm192(const float* __restrict__ W,
                                               const float* __restrict__ X,
                                               float* __restrict__ Y) {
  __shared__ float wlds[OT * 192];
  int tid = threadIdx.x;
  int p = blockIdx.x * 256 + tid;
  int o0 = blockIdx.y * OT;
  for (int i = tid; i < OT * 192; i += 256) wlds[i] = W[o0 * 192 + i];
  __syncthreads();
  float acc[OT];
  #pragma unroll
  for (int i = 0; i < OT; ++i) acc[i] = 0.f;
  // software-pipelined: X loads for c+4 issued before FMAs of c
  float x0 = X[0 * 4096 + p];
  float x1 = X[1 * 4096 + p];
  float x2 = X[2 * 4096 + p];
  float x3 = X[3 * 4096 + p];
  for (int c = 0; c < 192; c += 4) {
    float n0, n1, n2, n3;
    if (c < 188) {
      n0 = X[(c + 4) * 4096 + p];
      n1 = X[(c + 5) * 4096 + p];
      n2 = X[(c + 6) * 4096 + p];
      n3 = X[(c + 7) * 4096 + p];
    }
    #pragma unroll
    for (int oo = 0; oo < OT; ++oo) {
      const float4* wv = (const float4*)&wlds[oo * 192 + c];  // broadcast b128
      acc[oo] = fmaf(wv->x, x0, fmaf(wv->y, x1, fmaf(wv->z, x2, fmaf(wv->w, x3, acc[oo]))));
    }
    x0 = n0; x1 = n1; x2 = n2; x3 = n3;
  }
  #pragma unroll
  for (int oo = 0; oo < OT; ++oo) Y[(size_t)(o0 + oo) * 4096 + p] = acc[oo];
}

// ---- K2: depthwise 3x3, pad=1, on [576][64][64] ----
__global__ __launch_bounds__(256) void dwconv3(const float* __restrict__ in,
                                               const float* __restrict__ w,
                                               float* __restrict__ out) {
  int idx = blockIdx.x * 256 + threadIdx.x;  // c*4096 + p
  int c = idx >> 12;
  int p = idx & 4095;
  int y = p >> 6, x = p & 63;
  const float* wc = w + c * 9;
  const float* ic = in + (size_t)c * 4096;
  float s = 0.f;
  #pragma unroll
  for (int i = 0; i < 3; ++i) {
    int yy = y + i - 1;
    if ((unsigned)yy >= 64u) continue;
    #pragma unroll
    for (int j = 0; j < 3; ++j) {
      int xx = x + j - 1;
      if ((unsigned)xx >= 64u) continue;
      s = fmaf(wc[i * 3 + j], ic[yy * 64 + xx], s);
    }
  }
  out[idx] = s;
}

// ---- K3: fused normalize+pack. 256 blocks; per block: 128 pixels of one head.
// Threads 0..127: Q+K normalize+pack ([h][p][32] bf16). Threads 128..255: V pack
// (k-permuted [h][d][k'], row d==24 = ones -> PV MFMA yields softmax denominator).
__global__ __launch_bounds__(256) void nvpack(const float* __restrict__ qkv,
                                              u32* __restrict__ Qh32,
                                              u32* __restrict__ Kh32,
                                              u32* __restrict__ Vt32) {
  __shared__ u32 Ql[128 * 17];
  __shared__ u32 Kl[128 * 17];
  __shared__ u16 Vl[32 * 128];
  int t = threadIdx.x;
  int bid = blockIdx.x;          // 256 blocks
  int h = bid >> 5;
  int p0 = (bid & 31) << 7;      // 128-pixel tile
  u32* Vl32 = (u32*)Vl;
  const float QSC = 0.20412414523193154f * 1.4426950408889634f;  // 24^-0.5 * log2(e)
  if (t < 128) {
    int p = p0 + t;
    float qv[24], kv[24];
    float sq = 0.f, sk = 0.f;
    #pragma unroll
    for (int d = 0; d < 24; ++d) {
      qv[d] = qkv[(size_t)(h * 24 + d) * 4096 + p];
      sq = fmaf(qv[d], qv[d], sq);
    }
    #pragma unroll
    for (int d = 0; d < 24; ++d) {
      kv[d] = qkv[(size_t)(192 + h * 24 + d) * 4096 + p];
      sk = fmaf(kv[d], kv[d], sk);
    }
    float iq = QSC / fmaxf(sqrtf(sq), 1e-12f);  // F.normalize: x / max(||x||, eps)
    float ik = 1.0f / fmaxf(sqrtf(sk), 1e-12f);
    u32* qrow = Ql + t * 17;
    u32* krow = Kl + t * 17;
    #pragma unroll
    for (int j = 0; j < 12; ++j) {
      qrow[j] = ((u32)f2bf(qv[2 * j + 1] * iq) << 16) | f2bf(qv[2 * j] * iq);
      krow[j] = ((u32)f2bf(kv[2 * j + 1] * ik) << 16) | f2bf(kv[2 * j] * ik);
    }
    #pragma unroll
    for (int j = 12; j < 16; ++j) { qrow[j] = 0; krow[j] = 0; }
  } else {
    int tl = t - 128;
    int p = p0 + tl;
    int kp = (tl & ~63) | (((tl & 15) << 1) + ((tl >> 4) & 1) + (tl & 32));
    #pragma unroll
    for (int d = 0; d < 24; ++d)
      Vl[d * 128 + kp] = f2bf(qkv[(size_t)(384 + h * 24 + d) * 4096 + p]);
    Vl[24 * 128 + kp] = 0x3F80;  // bf16 1.0
  }
  for (int i = t; i < 7 * 64; i += 256) Vl32[25 * 64 + i] = 0;  // zero d=25..31
  __syncthreads();
  size_t base = ((size_t)(h << 12) + p0) * 16;
  for (int i = t; i < 2048; i += 256) {
    u32 li = (i >> 4) * 17 + (i & 15);
    Qh32[base + i] = Ql[li];
    Kh32[base + i] = Kl[li];
  }
  for (int i = t; i < 2048; i += 256) {
    int d = i >> 6, c = i & 63;
    Vt32[(((size_t)(h * 32 + d)) << 11) + (p0 >> 1) + c] = Vl32[d * 64 + c];
  }
}

#define PSTR 36  // dwords per P row (16B-aligned rows, 2-way-free banks)

// ---- K4: flash attention, 128 q/block (2 frags/wave), split-K 8, no barriers.
// No online max (logits bounded +-0.295 after log2e fold). Single P buffer (wave-
// private strips, in-order LDS) -> 18.4 KB -> 8 blocks/CU. Epilogue: PRIVATE
// per-split fp16 slabs (atomics in R5 caused 155 MB of cross-XCD HBM RMW traffic).
__global__ __launch_bounds__(256, 8) void attn(const u16* __restrict__ Qh,
                                               const u16* __restrict__ Kh,
                                               const u16* __restrict__ Vt,
                                               u16* __restrict__ pnum,
                                               u16* __restrict__ pden) {
  __shared__ u32 Pl[128 * PSTR];  // 18432 B
  int tid = threadIdx.x;
  int wave = tid >> 6, lane = tid & 63;
  int lo = lane & 15, hi = lane >> 4;
  int b = blockIdx.x;
  int head = b & 7;              // head == XCD (round-robin) -> K/V L2-resident per XCD
  int t = b >> 3;
  int q0 = (t & 31) << 7;        // 32 q-tiles of 128
  int ks = t >> 5;               // 0..7
  int kbase = ks << 9;           // 512 keys per split

  const u16* Kb = Kh + ((size_t)head << 17);
  const u16* Vb = Vt + ((size_t)head << 17);

  size_t qbase = ((size_t)(head << 12) + q0 + wave * 32 + lo) << 5;
  bf16x8 qf0 = *(const bf16x8*)(Qh + qbase + hi * 8);
  bf16x8 qf1 = *(const bf16x8*)(Qh + qbase + (16 << 5) + hi * 8);

  f32x4 o00 = {0.f, 0.f, 0.f, 0.f}, o01 = o00, o10 = o00, o11 = o00;

  int wr0 = (wave * 32 + hi * 4) * PSTR + lo;   // frag0 write base (dwords)
  int rd0 = (wave * 32 + lo) * PSTR + hi * 4;   // frag0 read base (dwords)

  bf16x8 kf[2][4];
  #pragma unroll
  for (int j = 0; j < 4; ++j)
    kf[0][j] = *(const bf16x8*)(Kb + (((size_t)(kbase + j * 16 + lo)) << 5) + hi * 8);

  #pragma unroll
  for (int it = 0; it < 8; ++it) {
    int cur = it & 1;
    int k0 = kbase + it * 64;
    // V for CURRENT iter (consumed at bottom, ~full body of latency cover)
    bf16x8 vf[4];
    #pragma unroll
    for (int c = 0; c < 2; ++c)
      #pragma unroll
      for (int n = 0; n < 2; ++n)
        vf[c * 2 + n] = *(const bf16x8*)(Vb + (((size_t)(n * 16 + lo)) << 12) + k0 + c * 32 + hi * 8);
    // K for NEXT iter
    if (it < 7) {
      #pragma unroll
      for (int j = 0; j < 4; ++j)
        kf[cur ^ 1][j] = *(const bf16x8*)(Kb + (((size_t)(k0 + 64 + j * 16 + lo)) << 5) + hi * 8);
    }

    f32x4 z = {0.f, 0.f, 0.f, 0.f};
    f32x4 s00 = __builtin_amdgcn_mfma_f32_16x16x32_bf16(qf0, kf[cur][0], z, 0, 0, 0);
    f32x4 s01 = __builtin_amdgcn_mfma_f32_16x16x32_bf16(qf0, kf[cur][1], z, 0, 0, 0);
    f32x4 s02 = __builtin_amdgcn_mfma_f32_16x16x32_bf16(qf0, kf[cur][2], z, 0, 0, 0);
    f32x4 s03 = __builtin_amdgcn_mfma_f32_16x16x32_bf16(qf0, kf[cur][3], z, 0, 0, 0);
    f32x4 s10 = __builtin_amdgcn_mfma_f32_16x16x32_bf16(qf1, kf[cur][0], z, 0, 0, 0);
    f32x4 s11 = __builtin_amdgcn_mfma_f32_16x16x32_bf16(qf1, kf[cur][1], z, 0, 0, 0);
    f32x4 s12 = __builtin_amdgcn_mfma_f32_16x16x32_bf16(qf1, kf[cur][2], z, 0, 0, 0);
    f32x4 s13 = __builtin_amdgcn_mfma_f32_16x16x32_bf16(qf1, kf[cur][3], z, 0, 0, 0);

    // frag0: exp + truncate-pack + LDS write, then read (latency covered by frag1 work)
    #pragma unroll
    for (int r = 0; r < 4; ++r) {
      u32 e0 = __float_as_uint(__builtin_amdgcn_exp2f(s00[r]));
      u32 e1 = __float_as_uint(__builtin_amdgcn_exp2f(s01[r]));
      u32 e2 = __float_as_uint(__builtin_amdgcn_exp2f(s02[r]));
      u32 e3 = __float_as_uint(__builtin_amdgcn_exp2f(s03[r]));
      Pl[wr0 + r * PSTR]      = __builtin_amdgcn_perm(e1, e0, 0x07060302u);
      Pl[wr0 + r * PSTR + 16] = __builtin_amdgcn_perm(e3, e2, 0x07060302u);
    }
    bf16x8 a00 = *(const bf16x8*)(&Pl[rd0]);
    bf16x8 a01 = *(const bf16x8*)(&Pl[rd0 + 16]);
    // frag1
    #pragma unroll
    for (int r = 0; r < 4; ++r) {
      u32 e0 = __float_as_uint(__builtin_amdgcn_exp2f(s10[r]));
      u32 e1 = __float_as_uint(__builtin_amdgcn_exp2f(s11[r]));
      u32 e2 = __float_as_uint(__builtin_amdgcn_exp2f(s12[r]));
      u32 e3 = __float_as_uint(__builtin_amdgcn_exp2f(s13[r]));
      Pl[wr0 + 16 * PSTR + r * PSTR]      = __builtin_amdgcn_perm(e1, e0, 0x07060302u);
      Pl[wr0 + 16 * PSTR + r * PSTR + 16] = __builtin_amdgcn_perm(e3, e2, 0x07060302u);
    }
    bf16x8 a10 = *(const bf16x8*)(&Pl[rd0 + 16 * PSTR]);
    bf16x8 a11 = *(const bf16x8*)(&Pl[rd0 + 16 * PSTR + 16]);

    o00 = __builtin_amdgcn_mfma_f32_16x16x32_bf16(a00, vf[0], o00, 0, 0, 0);
    o01 = __builtin_amdgcn_mfma_f32_16x16x32_bf16(a00, vf[1], o01, 0, 0, 0);
    o10 = __builtin_amdgcn_mfma_f32_16x16x32_bf16(a10, vf[0], o10, 0, 0, 0);
    o11 = __builtin_amdgcn_mfma_f32_16x16x32_bf16(a10, vf[1], o11, 0, 0, 0);
    o00 = __builtin_amdgcn_mfma_f32_16x16x32_bf16(a01, vf[2], o00, 0, 0, 0);
    o01 = __builtin_amdgcn_mfma_f32_16x16x32_bf16(a01, vf[3], o01, 0, 0, 0);
    o10 = __builtin_amdgcn_mfma_f32_16x16x32_bf16(a11, vf[2], o10, 0, 0, 0);
    o11 = __builtin_amdgcn_mfma_f32_16x16x32_bf16(a11, vf[3], o11, 0, 0, 0);
  }

  // epilogue: C-layout store into PRIVATE fp16 slab [ks][h][q][24] / [ks][h][q].
  // d = lo (o*0), 16+lo (o*1, lo<8); lo==8 of o*1 is the ones-row (denominator) sum.
  size_t qg = ((size_t)(ks * 8 + head) << 12) + q0 + wave * 32 + hi * 4;
  #pragma unroll
  for (int r = 0; r < 4; ++r) {
    u16* row0 = pnum + (qg + r) * 24;
    row0[lo] = f2h(o00[r]);
    if (lo < 8) row0[16 + lo] = f2h(o01[r]);
    if (lo == 8) pden[qg + r] = f2h(o01[r]);
    u16* row1 = pnum + (qg + 16 + r) * 24;
    row1[lo] = f2h(o10[r]);
    if (lo < 8) row1[16 + lo] = f2h(o11[r]);
    if (lo == 8) pden[qg + 16 + r] = f2h(o11[r]);
  }
}

// ---- K4b: combine 8 fp16 split slabs -> attn_o [192][4096] ----
__global__ __launch_bounds__(256) void combine(const u16* __restrict__ pnum,
                                               const u16* __restrict__ pden,
                                               float* __restrict__ Y) {
  int idx = blockIdx.x * 256 + threadIdx.x;  // (h,q): 8*4096
  int h = idx >> 12, q = idx & 4095;
  int dg = blockIdx.y * 8;
  float den = 0.f;
  #pragma unroll
  for (int s = 0; s < 8; ++s) den += h2f(pden[((size_t)(s * 8 + h) << 12) + q]);
  float inv = 1.0f / den;
  float acc[8];
  #pragma unroll
  for (int d = 0; d < 8; ++d) acc[d] = 0.f;
  #pragma unroll
  for (int s = 0; s < 8; ++s) {
    const u16* row = pnum + ((((size_t)(s * 8 + h) << 12) + q) * 24) + dg;
    #pragma unroll
    for (int j = 0; j < 4; ++j) {
      u32 pr = *(const u32*)(row + 2 * j);
      acc[2 * j]     += h2f((u16)(pr & 0xFFFF));
      acc[2 * j + 1] += h2f((u16)(pr >> 16));
    }
  }
  #pragma unroll
  for (int d = 0; d < 8; ++d)
    Y[(size_t)(h * 24 + dg + d) * 4096 + q] = acc[d] * inv;
}

extern "C" void kernel_launch(void* const* d_in, const int* in_sizes, int n_in,
                              void* d_out, int out_size, void* d_ws, size_t ws_size,
                              hipStream_t stream) {
  const float* x      = (const float*)d_in[0];  // [192][4096]
  const float* w_qkv  = (const float*)d_in[1];  // [576][192]
  const float* w_dw   = (const float*)d_in[2];  // [576][9]
  const float* w_proj = (const float*)d_in[3];  // [192][192]
  float* out = (float*)d_out;                   // [192][4096] fp32

  char* ws = (char*)d_ws;
  float* qkv    = (float*)(ws);                 // 9437184           (dead after dwconv3)
  float* qkvd   = (float*)(ws + 9437184);       // 9437184           (dead after nvpack)
  u16*   Qh     = (u16*)  (ws + 18874368);      // 2097152           (dead after attn)
  u16*   Kh     = (u16*)  (ws + 20971520);      // 2097152           (dead after attn)
  u16*   Vt     = (u16*)  (ws + 23068672);      // 2097152  (end 25165824; dead after attn)
  // attention outputs overlay the dead qkv/qkvd region:
  u16*   pnum   = (u16*)  (ws);                 // 8*8*4096*24*2 = 12582912 (fp16 slabs)
  u16*   pden   = (u16*)  (ws + 12582912);      // 8*8*4096*2   = 524288   (end 13107200)
  float* attn_o = (float*)(ws + 13107200);      // 192*4096*4   = 3145728  (end 16252928)

  // qkv GEMM, OT=8: grid (16,72)=1152 blocks = 4.5 blocks/CU
  gemm192<8><<<dim3(16, 72), 256, 0, stream>>>(w_qkv, x, qkv);
  dwconv3<<<dim3(9216), 256, 0, stream>>>(qkv, w_dw, qkvd);
  nvpack<<<dim3(256), 256, 0, stream>>>(qkvd, (u32*)Qh, (u32*)Kh, (u32*)Vt);
  // split-8: grid 2048 = 8 blocks/CU (LDS 18.4K x 8 = 147K <= 160K)
  attn<<<dim3(2048), 256, 0, stream>>>(Qh, Kh, Vt, pnum, pden);
  combine<<<dim3(128, 3), 256, 0, stream>>>(pnum, pden, attn_o);
  // proj GEMM, OT=4: grid (16,48)=768 blocks = 3 blocks/CU
  gemm192<4><<<dim3(16, 48), 256, 0, stream>>>(w_proj, attn_o, out);
}

// Round 8
// 194.843 us; speedup vs baseline: 1.1292x; 1.0178x over previous
//
#include <hip/hip_runtime.h>

typedef unsigned short u16;
typedef unsigned int u32;
typedef short bf16x8 __attribute__((ext_vector_type(8)));
typedef float f32x4 __attribute__((ext_vector_type(4)));

// float -> bf16 bits, round-to-nearest-even (inputs never NaN here)
__device__ __forceinline__ u16 f2bf(float f) {
  union { float f; unsigned int u; } a; a.f = f;
  unsigned int r = a.u + 0x7FFFu + ((a.u >> 16) & 1u);
  return (u16)(r >> 16);
}

// float -> fp16 bits / back (partial accumulators; |x| <= ~1e3, well inside fp16)
__device__ __forceinline__ u16 f2h(float f) {
  _Float16 h = (_Float16)f;
  return *(u16*)&h;
}
__device__ __forceinline__ float h2f(u16 b) {
  _Float16 h = *(_Float16*)&b;
  return (float)h;
}

// ---- K1/K5: Y[o][p] = sum_c W[o*192+c] * X[c*4096+p]; o-tile = OT rows ----
template <int OT>
__global__ __launch_bounds__(256) void gemm192(const float* __restrict__ W,
                                               const float* __restrict__ X,
                                               float* __restrict__ Y) {
  __shared__ float wlds[OT * 192];
  int tid = threadIdx.x;
  int p = blockIdx.x * 256 + tid;
  int o0 = blockIdx.y * OT;
  for (int i = tid; i < OT * 192; i += 256) wlds[i] = W[o0 * 192 + i];
  __syncthreads();
  float acc[OT];
  #pragma unroll
  for (int i = 0; i < OT; ++i) acc[i] = 0.f;
  // software-pipelined: X loads for c+4 issued before FMAs of c
  float x0 = X[0 * 4096 + p];
  float x1 = X[1 * 4096 + p];
  float x2 = X[2 * 4096 + p];
  float x3 = X[3 * 4096 + p];
  for (int c = 0; c < 192; c += 4) {
    float n0, n1, n2, n3;
    if (c < 188) {
      n0 = X[(c + 4) * 4096 + p];
      n1 = X[(c + 5) * 4096 + p];
      n2 = X[(c + 6) * 4096 + p];
      n3 = X[(c + 7) * 4096 + p];
    }
    #pragma unroll
    for (int oo = 0; oo < OT; ++oo) {
      const float4* wv = (const float4*)&wlds[oo * 192 + c];  // broadcast b128
      acc[oo] = fmaf(wv->x, x0, fmaf(wv->y, x1, fmaf(wv->z, x2, fmaf(wv->w, x3, acc[oo]))));
    }
    x0 = n0; x1 = n1; x2 = n2; x3 = n3;
  }
  #pragma unroll
  for (int oo = 0; oo < OT; ++oo) Y[(size_t)(o0 + oo) * 4096 + p] = acc[oo];
}

// ---- K2: depthwise 3x3, pad=1, on [576][64][64] ----
__global__ __launch_bounds__(256) void dwconv3(const float* __restrict__ in,
                                               const float* __restrict__ w,
                                               float* __restrict__ out) {
  int idx = blockIdx.x * 256 + threadIdx.x;  // c*4096 + p
  int c = idx >> 12;
  int p = idx & 4095;
  int y = p >> 6, x = p & 63;
  const float* wc = w + c * 9;
  const float* ic = in + (size_t)c * 4096;
  float s = 0.f;
  #pragma unroll
  for (int i = 0; i < 3; ++i) {
    int yy = y + i - 1;
    if ((unsigned)yy >= 64u) continue;
    #pragma unroll
    for (int j = 0; j < 3; ++j) {
      int xx = x + j - 1;
      if ((unsigned)xx >= 64u) continue;
      s = fmaf(wc[i * 3 + j], ic[yy * 64 + xx], s);
    }
  }
  out[idx] = s;
}

// ---- K3: fused normalize+pack. 256 blocks; per block: 128 pixels of one head.
// Threads 0..127: Q+K normalize+pack ([h][p][32] bf16). Threads 128..255: V pack
// (k-permuted [h][d][k'], row d==24 = ones -> PV MFMA yields softmax denominator).
__global__ __launch_bounds__(256) void nvpack(const float* __restrict__ qkv,
                                              u32* __restrict__ Qh32,
                                              u32* __restrict__ Kh32,
                                              u32* __restrict__ Vt32) {
  __shared__ u32 Ql[128 * 17];
  __shared__ u32 Kl[128 * 17];
  __shared__ u16 Vl[32 * 128];
  int t = threadIdx.x;
  int bid = blockIdx.x;          // 256 blocks
  int h = bid >> 5;
  int p0 = (bid & 31) << 7;      // 128-pixel tile
  u32* Vl32 = (u32*)Vl;
  const float QSC = 0.20412414523193154f * 1.4426950408889634f;  // 24^-0.5 * log2(e)
  if (t < 128) {
    int p = p0 + t;
    float qv[24], kv[24];
    float sq = 0.f, sk = 0.f;
    #pragma unroll
    for (int d = 0; d < 24; ++d) {
      qv[d] = qkv[(size_t)(h * 24 + d) * 4096 + p];
      sq = fmaf(qv[d], qv[d], sq);
    }
    #pragma unroll
    for (int d = 0; d < 24; ++d) {
      kv[d] = qkv[(size_t)(192 + h * 24 + d) * 4096 + p];
      sk = fmaf(kv[d], kv[d], sk);
    }
    float iq = QSC / fmaxf(sqrtf(sq), 1e-12f);  // F.normalize: x / max(||x||, eps)
    float ik = 1.0f / fmaxf(sqrtf(sk), 1e-12f);
    u32* qrow = Ql + t * 17;
    u32* krow = Kl + t * 17;
    #pragma unroll
    for (int j = 0; j < 12; ++j) {
      qrow[j] = ((u32)f2bf(qv[2 * j + 1] * iq) << 16) | f2bf(qv[2 * j] * iq);
      krow[j] = ((u32)f2bf(kv[2 * j + 1] * ik) << 16) | f2bf(kv[2 * j] * ik);
    }
    #pragma unroll
    for (int j = 12; j < 16; ++j) { qrow[j] = 0; krow[j] = 0; }
  } else {
    int tl = t - 128;
    int p = p0 + tl;
    int kp = (tl & ~63) | (((tl & 15) << 1) + ((tl >> 4) & 1) + (tl & 32));
    #pragma unroll
    for (int d = 0; d < 24; ++d)
      Vl[d * 128 + kp] = f2bf(qkv[(size_t)(384 + h * 24 + d) * 4096 + p]);
    Vl[24 * 128 + kp] = 0x3F80;  // bf16 1.0
  }
  for (int i = t; i < 7 * 64; i += 256) Vl32[25 * 64 + i] = 0;  // zero d=25..31
  __syncthreads();
  size_t base = ((size_t)(h << 12) + p0) * 16;
  for (int i = t; i < 2048; i += 256) {
    u32 li = (i >> 4) * 17 + (i & 15);
    Qh32[base + i] = Ql[li];
    Kh32[base + i] = Kl[li];
  }
  for (int i = t; i < 2048; i += 256) {
    int d = i >> 6, c = i & 63;
    Vt32[(((size_t)(h * 32 + d)) << 11) + (p0 >> 1) + c] = Vl32[d * 64 + c];
  }
}

#define PSTR 36  // dwords per P row (16B-aligned rows, 2-way-free banks)

// ---- K4: flash attention, 128 q/block (2 frags/wave), split-K 8, no barriers.
// No online max (logits bounded +-0.295 after log2e fold). Single P buffer (wave-
// private strips, in-order LDS) -> 18.4 KB -> 8 blocks/CU. Epilogue: private
// fp16 slabs written via LDS transpose as FULL COALESCED LINES; staging lives
// INSIDE this wave's own P strip (R7 staged into other waves' live P -> race/NaN).
__global__ __launch_bounds__(256, 8) void attn(const u16* __restrict__ Qh,
                                               const u16* __restrict__ Kh,
                                               const u16* __restrict__ Vt,
                                               u16* __restrict__ pnum,
                                               u16* __restrict__ pden) {
  __shared__ u32 Pl[128 * PSTR];  // 18432 B
  int tid = threadIdx.x;
  int wave = tid >> 6, lane = tid & 63;
  int lo = lane & 15, hi = lane >> 4;
  int b = blockIdx.x;
  int head = b & 7;              // head == XCD (round-robin) -> K/V L2-resident per XCD
  int t = b >> 3;
  int q0 = (t & 31) << 7;        // 32 q-tiles of 128
  int ks = t >> 5;               // 0..7
  int kbase = ks << 9;           // 512 keys per split

  const u16* Kb = Kh + ((size_t)head << 17);
  const u16* Vb = Vt + ((size_t)head << 17);

  size_t qbase = ((size_t)(head << 12) + q0 + wave * 32 + lo) << 5;
  bf16x8 qf0 = *(const bf16x8*)(Qh + qbase + hi * 8);
  bf16x8 qf1 = *(const bf16x8*)(Qh + qbase + (16 << 5) + hi * 8);

  f32x4 o00 = {0.f, 0.f, 0.f, 0.f}, o01 = o00, o10 = o00, o11 = o00;

  int wr0 = (wave * 32 + hi * 4) * PSTR + lo;   // frag0 write base (dwords)
  int rd0 = (wave * 32 + lo) * PSTR + hi * 4;   // frag0 read base (dwords)

  bf16x8 kf[2][4];
  #pragma unroll
  for (int j = 0; j < 4; ++j)
    kf[0][j] = *(const bf16x8*)(Kb + (((size_t)(kbase + j * 16 + lo)) << 5) + hi * 8);

  #pragma unroll
  for (int it = 0; it < 8; ++it) {
    int cur = it & 1;
    int k0 = kbase + it * 64;
    // V for CURRENT iter (consumed at bottom, ~full body of latency cover)
    bf16x8 vf[4];
    #pragma unroll
    for (int c = 0; c < 2; ++c)
      #pragma unroll
      for (int n = 0; n < 2; ++n)
        vf[c * 2 + n] = *(const bf16x8*)(Vb + (((size_t)(n * 16 + lo)) << 12) + k0 + c * 32 + hi * 8);
    // K for NEXT iter
    if (it < 7) {
      #pragma unroll
      for (int j = 0; j < 4; ++j)
        kf[cur ^ 1][j] = *(const bf16x8*)(Kb + (((size_t)(k0 + 64 + j * 16 + lo)) << 5) + hi * 8);
    }

    f32x4 z = {0.f, 0.f, 0.f, 0.f};
    f32x4 s00 = __builtin_amdgcn_mfma_f32_16x16x32_bf16(qf0, kf[cur][0], z, 0, 0, 0);
    f32x4 s01 = __builtin_amdgcn_mfma_f32_16x16x32_bf16(qf0, kf[cur][1], z, 0, 0, 0);
    f32x4 s02 = __builtin_amdgcn_mfma_f32_16x16x32_bf16(qf0, kf[cur][2], z, 0, 0, 0);
    f32x4 s03 = __builtin_amdgcn_mfma_f32_16x16x32_bf16(qf0, kf[cur][3], z, 0, 0, 0);
    f32x4 s10 = __builtin_amdgcn_mfma_f32_16x16x32_bf16(qf1, kf[cur][0], z, 0, 0, 0);
    f32x4 s11 = __builtin_amdgcn_mfma_f32_16x16x32_bf16(qf1, kf[cur][1], z, 0, 0, 0);
    f32x4 s12 = __builtin_amdgcn_mfma_f32_16x16x32_bf16(qf1, kf[cur][2], z, 0, 0, 0);
    f32x4 s13 = __builtin_amdgcn_mfma_f32_16x16x32_bf16(qf1, kf[cur][3], z, 0, 0, 0);

    // frag0: exp + truncate-pack + LDS write, then read (latency covered by frag1 work)
    #pragma unroll
    for (int r = 0; r < 4; ++r) {
      u32 e0 = __float_as_uint(__builtin_amdgcn_exp2f(s00[r]));
      u32 e1 = __float_as_uint(__builtin_amdgcn_exp2f(s01[r]));
      u32 e2 = __float_as_uint(__builtin_amdgcn_exp2f(s02[r]));
      u32 e3 = __float_as_uint(__builtin_amdgcn_exp2f(s03[r]));
      Pl[wr0 + r * PSTR]      = __builtin_amdgcn_perm(e1, e0, 0x07060302u);
      Pl[wr0 + r * PSTR + 16] = __builtin_amdgcn_perm(e3, e2, 0x07060302u);
    }
    bf16x8 a00 = *(const bf16x8*)(&Pl[rd0]);
    bf16x8 a01 = *(const bf16x8*)(&Pl[rd0 + 16]);
    // frag1
    #pragma unroll
    for (int r = 0; r < 4; ++r) {
      u32 e0 = __float_as_uint(__builtin_amdgcn_exp2f(s10[r]));
      u32 e1 = __float_as_uint(__builtin_amdgcn_exp2f(s11[r]));
      u32 e2 = __float_as_uint(__builtin_amdgcn_exp2f(s12[r]));
      u32 e3 = __float_as_uint(__builtin_amdgcn_exp2f(s13[r]));
      Pl[wr0 + 16 * PSTR + r * PSTR]      = __builtin_amdgcn_perm(e1, e0, 0x07060302u);
      Pl[wr0 + 16 * PSTR + r * PSTR + 16] = __builtin_amdgcn_perm(e3, e2, 0x07060302u);
    }
    bf16x8 a10 = *(const bf16x8*)(&Pl[rd0 + 16 * PSTR]);
    bf16x8 a11 = *(const bf16x8*)(&Pl[rd0 + 16 * PSTR + 16]);

    o00 = __builtin_amdgcn_mfma_f32_16x16x32_bf16(a00, vf[0], o00, 0, 0, 0);
    o01 = __builtin_amdgcn_mfma_f32_16x16x32_bf16(a00, vf[1], o01, 0, 0, 0);
    o10 = __builtin_amdgcn_mfma_f32_16x16x32_bf16(a10, vf[0], o10, 0, 0, 0);
    o11 = __builtin_amdgcn_mfma_f32_16x16x32_bf16(a10, vf[1], o11, 0, 0, 0);
    o00 = __builtin_amdgcn_mfma_f32_16x16x32_bf16(a01, vf[2], o00, 0, 0, 0);
    o01 = __builtin_amdgcn_mfma_f32_16x16x32_bf16(a01, vf[3], o01, 0, 0, 0);
    o10 = __builtin_amdgcn_mfma_f32_16x16x32_bf16(a11, vf[2], o10, 0, 0, 0);
    o11 = __builtin_amdgcn_mfma_f32_16x16x32_bf16(a11, vf[3], o11, 0, 0, 0);
  }

  // ---- epilogue: stage C-layout into THIS WAVE'S OWN P strip (u16 view),
  // then store as full coalesced lines. Slab row = 24 fp16 (12 u32); den at col 24.
  // Wave strip = 32*PSTR u32 = 1152 u32; staging needs 32*RS/2 = 448 u32. No
  // cross-wave overlap (R7 bug). Intra-wave write-after-read is safe (in-order LDS).
  u16* Sl = (u16*)Pl;
  const int RS = 28;                      // u16 stride per staged row (u32-aligned)
  int ws16 = wave * 32 * PSTR * 2;        // u16 base of this wave's strip
  #pragma unroll
  for (int r = 0; r < 4; ++r) {
    int row0 = hi * 4 + r;                // frag0 -> rows 0..15
    Sl[ws16 + row0 * RS + lo] = f2h(o00[r]);
    if (lo < 8) Sl[ws16 + row0 * RS + 16 + lo] = f2h(o01[r]);
    if (lo == 8) Sl[ws16 + row0 * RS + 24] = f2h(o01[r]);  // ones-row = den
    int row1 = 16 + hi * 4 + r;           // frag1 -> rows 16..31
    Sl[ws16 + row1 * RS + lo] = f2h(o10[r]);
    if (lo < 8) Sl[ws16 + row1 * RS + 16 + lo] = f2h(o11[r]);
    if (lo == 8) Sl[ws16 + row1 * RS + 24] = f2h(o11[r]);
  }
  // wave-private LDS: in-order, no barrier. Coalesced u32 stores: 256 B/instr.
  const u32* Sl32 = (const u32*)Sl;
  int ws32 = wave * 32 * PSTR;            // u32 base of this wave's strip
  size_t qgw = ((size_t)(ks * 8 + head) << 12) + q0 + wave * 32;  // global slab row
  u32* pnum32 = (u32*)pnum;
  #pragma unroll
  for (int i = lane; i < 32 * 12; i += 64) {
    int row = i / 12;
    int j = i - row * 12;
    pnum32[(qgw + row) * 12 + j] = Sl32[ws32 + row * (RS / 2) + j];
  }
  if (lane < 32) pden[qgw + lane] = Sl[ws16 + lane * RS + 24];
}

// ---- K4b: combine 8 fp16 split slabs -> attn_o [192][4096] ----
__global__ __launch_bounds__(256) void combine(const u16* __restrict__ pnum,
                                               const u16* __restrict__ pden,
                                               float* __restrict__ Y) {
  int idx = blockIdx.x * 256 + threadIdx.x;  // (h,q): 8*4096
  int h = idx >> 12, q = idx & 4095;
  int dg = blockIdx.y * 8;
  float den = 0.f;
  #pragma unroll
  for (int s = 0; s < 8; ++s) den += h2f(pden[((size_t)(s * 8 + h) << 12) + q]);
  float inv = 1.0f / den;
  float acc[8];
  #pragma unroll
  for (int d = 0; d < 8; ++d) acc[d] = 0.f;
  #pragma unroll
  for (int s = 0; s < 8; ++s) {
    const u16* row = pnum + ((((size_t)(s * 8 + h) << 12) + q) * 24) + dg;
    #pragma unroll
    for (int j = 0; j < 4; ++j) {
      u32 pr = *(const u32*)(row + 2 * j);
      acc[2 * j]     += h2f((u16)(pr & 0xFFFF));
      acc[2 * j + 1] += h2f((u16)(pr >> 16));
    }
  }
  #pragma unroll
  for (int d = 0; d < 8; ++d)
    Y[(size_t)(h * 24 + dg + d) * 4096 + q] = acc[d] * inv;
}

extern "C" void kernel_launch(void* const* d_in, const int* in_sizes, int n_in,
                              void* d_out, int out_size, void* d_ws, size_t ws_size,
                              hipStream_t stream) {
  const float* x      = (const float*)d_in[0];  // [192][4096]
  const float* w_qkv  = (const float*)d_in[1];  // [576][192]
  const float* w_dw   = (const float*)d_in[2];  // [576][9]
  const float* w_proj = (const float*)d_in[3];  // [192][192]
  float* out = (float*)d_out;                   // [192][4096] fp32

  char* ws = (char*)d_ws;
  float* qkv    = (float*)(ws);                 // 9437184           (dead after dwconv3)
  float* qkvd   = (float*)(ws + 9437184);       // 9437184           (dead after nvpack)
  u16*   Qh     = (u16*)  (ws + 18874368);      // 2097152           (dead after attn)
  u16*   Kh     = (u16*)  (ws + 20971520);      // 2097152           (dead after attn)
  u16*   Vt     = (u16*)  (ws + 23068672);      // 2097152  (end 25165824; dead after attn)
  // attention outputs overlay the dead qkv/qkvd region:
  u16*   pnum   = (u16*)  (ws);                 // 8*8*4096*24*2 = 12582912 (fp16 slabs)
  u16*   pden   = (u16*)  (ws + 12582912);      // 8*8*4096*2   = 524288   (end 13107200)
  float* attn_o = (float*)(ws + 13107200);      // 192*4096*4   = 3145728  (end 16252928)

  // qkv GEMM, OT=6: grid (16,96)=1536 blocks = 6 blocks/CU
  gemm192<6><<<dim3(16, 96), 256, 0, stream>>>(w_qkv, x, qkv);
  dwconv3<<<dim3(9216), 256, 0, stream>>>(qkv, w_dw, qkvd);
  nvpack<<<dim3(256), 256, 0, stream>>>(qkvd, (u32*)Qh, (u32*)Kh, (u32*)Vt);
  // split-8: grid 2048 = 8 blocks/CU (LDS 18.4K x 8 = 147K <= 160K)
  attn<<<dim3(2048), 256, 0, stream>>>(Qh, Kh, Vt, pnum, pden);
  combine<<<dim3(128, 3), 256, 0, stream>>>(pnum, pden, attn_o);
  // proj GEMM, OT=3: grid (16,64)=1024 blocks = 4 blocks/CU
  gemm192<3><<<dim3(16, 64), 256, 0, stream>>>(w_proj, attn_o, out);
}

// Round 9
// 171.596 us; speedup vs baseline: 1.2822x; 1.1355x over previous
//
#include <hip/hip_runtime.h>

typedef unsigned short u16;
typedef unsigned int u32;
typedef short bf16x8 __attribute__((ext_vector_type(8)));
typedef float f32x4 __attribute__((ext_vector_type(4)));

// float -> bf16 bits, round-to-nearest-even (inputs never NaN here)
__device__ __forceinline__ u16 f2bf(float f) {
  union { float f; unsigned int u; } a; a.f = f;
  unsigned int r = a.u + 0x7FFFu + ((a.u >> 16) & 1u);
  return (u16)(r >> 16);
}

// ---- K1/K5: Y[o][p] = sum_c W[o*192+c] * X[c*4096+p]; o-tile = OT rows ----
template <int OT>
__global__ __launch_bounds__(256) void gemm192(const float* __restrict__ W,
                                               const float* __restrict__ X,
                                               float* __restrict__ Y) {
  __shared__ float wlds[OT * 192];
  int tid = threadIdx.x;
  int p = blockIdx.x * 256 + tid;
  int o0 = blockIdx.y * OT;
  for (int i = tid; i < OT * 192; i += 256) wlds[i] = W[o0 * 192 + i];
  __syncthreads();
  float acc[OT];
  #pragma unroll
  for (int i = 0; i < OT; ++i) acc[i] = 0.f;
  // software-pipelined: X loads for c+4 issued before FMAs of c
  float x0 = X[0 * 4096 + p];
  float x1 = X[1 * 4096 + p];
  float x2 = X[2 * 4096 + p];
  float x3 = X[3 * 4096 + p];
  for (int c = 0; c < 192; c += 4) {
    float n0, n1, n2, n3;
    if (c < 188) {
      n0 = X[(c + 4) * 4096 + p];
      n1 = X[(c + 5) * 4096 + p];
      n2 = X[(c + 6) * 4096 + p];
      n3 = X[(c + 7) * 4096 + p];
    }
    #pragma unroll
    for (int oo = 0; oo < OT; ++oo) {
      const float4* wv = (const float4*)&wlds[oo * 192 + c];  // broadcast b128
      acc[oo] = fmaf(wv->x, x0, fmaf(wv->y, x1, fmaf(wv->z, x2, fmaf(wv->w, x3, acc[oo]))));
    }
    x0 = n0; x1 = n1; x2 = n2; x3 = n3;
  }
  #pragma unroll
  for (int oo = 0; oo < OT; ++oo) Y[(size_t)(o0 + oo) * 4096 + p] = acc[oo];
}

// ---- K2: depthwise 3x3, pad=1, on [576][64][64] ----
__global__ __launch_bounds__(256) void dwconv3(const float* __restrict__ in,
                                               const float* __restrict__ w,
                                               float* __restrict__ out) {
  int idx = blockIdx.x * 256 + threadIdx.x;  // c*4096 + p
  int c = idx >> 12;
  int p = idx & 4095;
  int y = p >> 6, x = p & 63;
  const float* wc = w + c * 9;
  const float* ic = in + (size_t)c * 4096;
  float s = 0.f;
  #pragma unroll
  for (int i = 0; i < 3; ++i) {
    int yy = y + i - 1;
    if ((unsigned)yy >= 64u) continue;
    #pragma unroll
    for (int j = 0; j < 3; ++j) {
      int xx = x + j - 1;
      if ((unsigned)xx >= 64u) continue;
      s = fmaf(wc[i * 3 + j], ic[yy * 64 + xx], s);
    }
  }
  out[idx] = s;
}

// ---- K3: fused normalize+pack. 256 blocks; per block: 128 pixels of one head.
// Threads 0..127: Q+K normalize+pack ([h][p][32] bf16). Threads 128..255: V pack
// (k-permuted [h][d][k'], row d==24 = ones -> PV MFMA yields softmax denominator).
__global__ __launch_bounds__(256) void nvpack(const float* __restrict__ qkv,
                                              u32* __restrict__ Qh32,
                                              u32* __restrict__ Kh32,
                                              u32* __restrict__ Vt32) {
  __shared__ u32 Ql[128 * 17];
  __shared__ u32 Kl[128 * 17];
  __shared__ u16 Vl[32 * 128];
  int t = threadIdx.x;
  int bid = blockIdx.x;          // 256 blocks
  int h = bid >> 5;
  int p0 = (bid & 31) << 7;      // 128-pixel tile
  u32* Vl32 = (u32*)Vl;
  const float QSC = 0.20412414523193154f * 1.4426950408889634f;  // 24^-0.5 * log2(e)
  if (t < 128) {
    int p = p0 + t;
    float qv[24], kv[24];
    float sq = 0.f, sk = 0.f;
    #pragma unroll
    for (int d = 0; d < 24; ++d) {
      qv[d] = qkv[(size_t)(h * 24 + d) * 4096 + p];
      sq = fmaf(qv[d], qv[d], sq);
    }
    #pragma unroll
    for (int d = 0; d < 24; ++d) {
      kv[d] = qkv[(size_t)(192 + h * 24 + d) * 4096 + p];
      sk = fmaf(kv[d], kv[d], sk);
    }
    float iq = QSC / fmaxf(sqrtf(sq), 1e-12f);  // F.normalize: x / max(||x||, eps)
    float ik = 1.0f / fmaxf(sqrtf(sk), 1e-12f);
    u32* qrow = Ql + t * 17;
    u32* krow = Kl + t * 17;
    #pragma unroll
    for (int j = 0; j < 12; ++j) {
      qrow[j] = ((u32)f2bf(qv[2 * j + 1] * iq) << 16) | f2bf(qv[2 * j] * iq);
      krow[j] = ((u32)f2bf(kv[2 * j + 1] * ik) << 16) | f2bf(kv[2 * j] * ik);
    }
    #pragma unroll
    for (int j = 12; j < 16; ++j) { qrow[j] = 0; krow[j] = 0; }
  } else {
    int tl = t - 128;
    int p = p0 + tl;
    int kp = (tl & ~63) | (((tl & 15) << 1) + ((tl >> 4) & 1) + (tl & 32));
    #pragma unroll
    for (int d = 0; d < 24; ++d)
      Vl[d * 128 + kp] = f2bf(qkv[(size_t)(384 + h * 24 + d) * 4096 + p]);
    Vl[24 * 128 + kp] = 0x3F80;  // bf16 1.0
  }
  for (int i = t; i < 7 * 64; i += 256) Vl32[25 * 64 + i] = 0;  // zero d=25..31
  __syncthreads();
  size_t base = ((size_t)(h << 12) + p0) * 16;
  for (int i = t; i < 2048; i += 256) {
    u32 li = (i >> 4) * 17 + (i & 15);
    Qh32[base + i] = Ql[li];
    Kh32[base + i] = Kl[li];
  }
  for (int i = t; i < 2048; i += 256) {
    int d = i >> 6, c = i & 63;
    Vt32[(((size_t)(h * 32 + d)) << 11) + (p0 >> 1) + c] = Vl32[d * 64 + c];
  }
}

#define PSTR 36  // dwords per P row (16B-aligned rows, 2-way-free banks)

// One 64-key tile: S = Q*K^T (MFMA), P = exp2(S) truncate-packed through this
// wave's LDS strip, O += P*V (MFMA). KC = current K frags, KN = prefetch target.
#define ATTN_TILE(K0, KC, KN, PF)                                               \
  do {                                                                          \
    bf16x8 vf0 = *(const bf16x8*)(Vb + (((size_t)(lo)) << 12) + (K0) + hi * 8);        \
    bf16x8 vf1 = *(const bf16x8*)(Vb + (((size_t)(16 + lo)) << 12) + (K0) + hi * 8);   \
    bf16x8 vf2 = *(const bf16x8*)(Vb + (((size_t)(lo)) << 12) + (K0) + 32 + hi * 8);   \
    bf16x8 vf3 = *(const bf16x8*)(Vb + (((size_t)(16 + lo)) << 12) + (K0) + 32 + hi * 8); \
    if (PF) {                                                                   \
      KN[0] = *(const bf16x8*)(Kb + (((size_t)((K0) + 64 + lo)) << 5) + hi * 8);  \
      KN[1] = *(const bf16x8*)(Kb + (((size_t)((K0) + 80 + lo)) << 5) + hi * 8);  \
      KN[2] = *(const bf16x8*)(Kb + (((size_t)((K0) + 96 + lo)) << 5) + hi * 8);  \
      KN[3] = *(const bf16x8*)(Kb + (((size_t)((K0) + 112 + lo)) << 5) + hi * 8); \
    }                                                                           \
    f32x4 z = {0.f, 0.f, 0.f, 0.f};                                             \
    f32x4 s00 = __builtin_amdgcn_mfma_f32_16x16x32_bf16(qf0, KC[0], z, 0, 0, 0); \
    f32x4 s01 = __builtin_amdgcn_mfma_f32_16x16x32_bf16(qf0, KC[1], z, 0, 0, 0); \
    f32x4 s02 = __builtin_amdgcn_mfma_f32_16x16x32_bf16(qf0, KC[2], z, 0, 0, 0); \
    f32x4 s03 = __builtin_amdgcn_mfma_f32_16x16x32_bf16(qf0, KC[3], z, 0, 0, 0); \
    f32x4 s10 = __builtin_amdgcn_mfma_f32_16x16x32_bf16(qf1, KC[0], z, 0, 0, 0); \
    f32x4 s11 = __builtin_amdgcn_mfma_f32_16x16x32_bf16(qf1, KC[1], z, 0, 0, 0); \
    f32x4 s12 = __builtin_amdgcn_mfma_f32_16x16x32_bf16(qf1, KC[2], z, 0, 0, 0); \
    f32x4 s13 = __builtin_amdgcn_mfma_f32_16x16x32_bf16(qf1, KC[3], z, 0, 0, 0); \
    for (int r = 0; r < 4; ++r) {                                               \
      u32 e0 = __float_as_uint(__builtin_amdgcn_exp2f(s00[r]));                 \
      u32 e1 = __float_as_uint(__builtin_amdgcn_exp2f(s01[r]));                 \
      u32 e2 = __float_as_uint(__builtin_amdgcn_exp2f(s02[r]));                 \
      u32 e3 = __float_as_uint(__builtin_amdgcn_exp2f(s03[r]));                 \
      Pl[wr0 + r * PSTR]      = __builtin_amdgcn_perm(e1, e0, 0x07060302u);     \
      Pl[wr0 + r * PSTR + 16] = __builtin_amdgcn_perm(e3, e2, 0x07060302u);     \
    }                                                                           \
    bf16x8 a00 = *(const bf16x8*)(&Pl[rd0]);                                    \
    bf16x8 a01 = *(const bf16x8*)(&Pl[rd0 + 16]);                               \
    for (int r = 0; r < 4; ++r) {                                               \
      u32 e0 = __float_as_uint(__builtin_amdgcn_exp2f(s10[r]));                 \
      u32 e1 = __float_as_uint(__builtin_amdgcn_exp2f(s11[r]));                 \
      u32 e2 = __float_as_uint(__builtin_amdgcn_exp2f(s12[r]));                 \
      u32 e3 = __float_as_uint(__builtin_amdgcn_exp2f(s13[r]));                 \
      Pl[wr0 + 16 * PSTR + r * PSTR]      = __builtin_amdgcn_perm(e1, e0, 0x07060302u); \
      Pl[wr0 + 16 * PSTR + r * PSTR + 16] = __builtin_amdgcn_perm(e3, e2, 0x07060302u); \
    }                                                                           \
    bf16x8 a10 = *(const bf16x8*)(&Pl[rd0 + 16 * PSTR]);                        \
    bf16x8 a11 = *(const bf16x8*)(&Pl[rd0 + 16 * PSTR + 16]);                   \
    o00 = __builtin_amdgcn_mfma_f32_16x16x32_bf16(a00, vf0, o00, 0, 0, 0);      \
    o01 = __builtin_amdgcn_mfma_f32_16x16x32_bf16(a00, vf1, o01, 0, 0, 0);      \
    o10 = __builtin_amdgcn_mfma_f32_16x16x32_bf16(a10, vf0, o10, 0, 0, 0);      \
    o11 = __builtin_amdgcn_mfma_f32_16x16x32_bf16(a10, vf1, o11, 0, 0, 0);      \
    o00 = __builtin_amdgcn_mfma_f32_16x16x32_bf16(a01, vf2, o00, 0, 0, 0);      \
    o01 = __builtin_amdgcn_mfma_f32_16x16x32_bf16(a01, vf3, o01, 0, 0, 0);      \
    o10 = __builtin_amdgcn_mfma_f32_16x16x32_bf16(a11, vf2, o10, 0, 0, 0);      \
    o11 = __builtin_amdgcn_mfma_f32_16x16x32_bf16(a11, vf3, o11, 0, 0, 0);      \
  } while (0)

// ---- K4: flash attention, NO intermediate slabs. 512-thread blocks (8 waves =
// 4 K-quarters x 2 Q-subgroups of 32 q). Grid = 8 heads x 64 q-tiles = 512
// blocks = 2/CU. Cross-wave (num,den) reduction in LDS, direct attn_o write.
// No online max (logits bounded +-0.295 after log2e fold). R5-R8 lesson: any
// global intermediate (atomics or slabs) costs 60-110 MB of HBM churn.
__global__ __launch_bounds__(512, 4) void attn(const u16* __restrict__ Qh,
                                               const u16* __restrict__ Kh,
                                               const u16* __restrict__ Vt,
                                               float* __restrict__ Y) {
  __shared__ u32 Pl[8 * 32 * PSTR];  // 36864 B: 8 wave-private strips
  int tid = threadIdx.x;
  int wave = tid >> 6, lane = tid & 63;
  int lo = lane & 15, hi = lane >> 4;
  int qg = wave & 1;             // Q subgroup (32 rows)
  int kh = wave >> 1;            // K quarter (1024 keys)
  int b = blockIdx.x;
  int head = b & 7;              // head == XCD (round-robin) -> K/V L2-resident
  int q0 = (b >> 3) << 6;        // 64 queries per block

  const u16* Kb = Kh + ((size_t)head << 17);
  const u16* Vb = Vt + ((size_t)head << 17);

  size_t qrow = (size_t)(head << 12) + q0 + qg * 32 + lo;
  bf16x8 qf0 = *(const bf16x8*)(Qh + (qrow << 5) + hi * 8);
  bf16x8 qf1 = *(const bf16x8*)(Qh + ((qrow + 16) << 5) + hi * 8);

  f32x4 o00 = {0.f, 0.f, 0.f, 0.f}, o01 = o00, o10 = o00, o11 = o00;

  int wr0 = (wave * 32 + hi * 4) * PSTR + lo;   // frag0 write base (dwords)
  int rd0 = (wave * 32 + lo) * PSTR + hi * 4;   // frag0 read base (dwords)
  int kbase = kh << 10;                         // 1024 keys per wave

  bf16x8 kfA[4], kfB[4];
  kfA[0] = *(const bf16x8*)(Kb + (((size_t)(kbase + lo)) << 5) + hi * 8);
  kfA[1] = *(const bf16x8*)(Kb + (((size_t)(kbase + 16 + lo)) << 5) + hi * 8);
  kfA[2] = *(const bf16x8*)(Kb + (((size_t)(kbase + 32 + lo)) << 5) + hi * 8);
  kfA[3] = *(const bf16x8*)(Kb + (((size_t)(kbase + 48 + lo)) << 5) + hi * 8);

  for (int it2 = 0; it2 < 8; ++it2) {           // 16 tiles of 64 keys
    int k0 = kbase + it2 * 128;
    ATTN_TILE(k0, kfA, kfB, 1);
    ATTN_TILE(k0 + 64, kfB, kfA, (it2 < 7));
  }

  // phase 1: stage fp32 C-layout (num cols 0..23, den col 24) into OWN strip.
  // In-order per wave (strip's P reads already done); stride 28 (<=PSTR*32/32).
  float* Sf = (float*)Pl;
  int sb = wave * (32 * PSTR);
  #pragma unroll
  for (int r = 0; r < 4; ++r) {
    int row0 = hi * 4 + r;
    Sf[sb + row0 * 28 + lo] = o00[r];
    if (lo < 8) Sf[sb + row0 * 28 + 16 + lo] = o01[r];
    if (lo == 8) Sf[sb + row0 * 28 + 24] = o01[r];   // ones-row = denominator
    int row1 = 16 + hi * 4 + r;
    Sf[sb + row1 * 28 + lo] = o10[r];
    if (lo < 8) Sf[sb + row1 * 28 + 16 + lo] = o11[r];
    if (lo == 8) Sf[sb + row1 * 28 + 24] = o11[r];
  }
  __syncthreads();
  // phase 2: reduce the 4 K-quarters, normalize, direct coalesced store.
  int q = tid & 63;
  int d0 = tid >> 6;             // 0..7
  int row = q & 31;
  int base0 = (q >> 5) * (32 * PSTR) + row * 28;  // strips qg, qg+2, qg+4, qg+6
  const int SS = 2 * 32 * PSTR;
  float den = Sf[base0 + 24] + Sf[base0 + SS + 24] +
              Sf[base0 + 2 * SS + 24] + Sf[base0 + 3 * SS + 24];
  float inv = 1.0f / den;
  float* Yh = Y + ((size_t)head * 24) * 4096 + q0 + q;
  #pragma unroll
  for (int dp = 0; dp < 3; ++dp) {
    int dd = dp * 8 + d0;
    float v = Sf[base0 + dd] + Sf[base0 + SS + dd] +
              Sf[base0 + 2 * SS + dd] + Sf[base0 + 3 * SS + dd];
    Yh[(size_t)dd * 4096] = v * inv;
  }
}

extern "C" void kernel_launch(void* const* d_in, const int* in_sizes, int n_in,
                              void* d_out, int out_size, void* d_ws, size_t ws_size,
                              hipStream_t stream) {
  const float* x      = (const float*)d_in[0];  // [192][4096]
  const float* w_qkv  = (const float*)d_in[1];  // [576][192]
  const float* w_dw   = (const float*)d_in[2];  // [576][9]
  const float* w_proj = (const float*)d_in[3];  // [192][192]
  float* out = (float*)d_out;                   // [192][4096] fp32

  char* ws = (char*)d_ws;
  float* qkv    = (float*)(ws);                 // 9437184           (dead after dwconv3)
  float* qkvd   = (float*)(ws + 9437184);       // 9437184           (dead after nvpack)
  u16*   Qh     = (u16*)  (ws + 18874368);      // 2097152
  u16*   Kh     = (u16*)  (ws + 20971520);      // 2097152
  u16*   Vt     = (u16*)  (ws + 23068672);      // 2097152  (end 25165824)
  float* attn_o = (float*)(ws + 13107200);      // 3145728, inside dead qkvd region

  // qkv GEMM, OT=6: grid (16,96)=1536 blocks = 6 blocks/CU
  gemm192<6><<<dim3(16, 96), 256, 0, stream>>>(w_qkv, x, qkv);
  dwconv3<<<dim3(9216), 256, 0, stream>>>(qkv, w_dw, qkvd);
  nvpack<<<dim3(256), 256, 0, stream>>>(qkvd, (u32*)Qh, (u32*)Kh, (u32*)Vt);
  // 512 blocks x 512 threads = 2 blocks/CU, 4 waves/SIMD, zero global intermediates
  attn<<<dim3(512), 512, 0, stream>>>(Qh, Kh, Vt, attn_o);
  // proj GEMM, OT=3: grid (16,64)=1024 blocks = 4 blocks/CU
  gemm192<3><<<dim3(16, 64), 256, 0, stream>>>(w_proj, attn_o, out);
}